// Round 1
// 6116.106 us; speedup vs baseline: 1.4083x; 1.4083x over previous
//
#include <hip/hip_runtime.h>
#include <cmath>

// Problem constants
constexpr int B_  = 16;    // batch
constexpr int N_  = 64;    // frames (scan length)
constexpr int K_  = 20;    // objects incl. image slot
constexpr int KM1 = 19;    // objects
constexpr int D_  = 4096;  // input feature dim
constexpr int DO_ = 1024;
constexpr int H_  = 1024;
constexpr int G4_ = 4096;  // 4*H

typedef unsigned short u16;
typedef unsigned int   u32;
typedef __attribute__((ext_vector_type(8))) short bf16x8;  // 8 bf16 = 4 VGPR
typedef __attribute__((ext_vector_type(4))) float f32x4;

typedef const void __attribute__((address_space(1)))* gas1_t;
typedef void __attribute__((address_space(3)))* las3_t;

static __device__ __forceinline__ void gll16(const void* g, void* l) {
  // async global->LDS, 16B per lane; LDS dest is wave-uniform base + lane*16
  __builtin_amdgcn_global_load_lds((gas1_t)g, (las3_t)l, 16, 0, 0);
}

static __device__ __forceinline__ float sigmoidf_(float x) {
  return 1.0f / (1.0f + expf(-x));
}

// round-to-nearest-even fp32 -> bf16 bits
static __device__ __forceinline__ u16 bf16rne(float f) {
  u32 u = __float_as_uint(f);
  return (u16)((u + 0x7fffu + ((u >> 16) & 1u)) >> 16);
}

// 256-thread (4-wave) block sum reduction
static __device__ __forceinline__ float block_reduce_sum256(float v, float* red) {
  #pragma unroll
  for (int off = 32; off > 0; off >>= 1) v += __shfl_down(v, off);
  const int wid = threadIdx.x >> 6;
  if ((threadIdx.x & 63) == 0) red[wid] = v;
  __syncthreads();
  const float r = red[0] + red[1] + red[2] + red[3];
  __syncthreads();
  return r;
}

// obj_mask[r] = sum_d x[b, n, 1+kk, d],  r = (b*N + n)*19 + kk
__global__ __launch_bounds__(256) void mask_kernel(const float* __restrict__ x,
                                                   float* __restrict__ mask) {
  const int r = blockIdx.x;
  const int g = r / KM1, kk = r - g * KM1;
  const float4* xp = (const float4*)(x + ((size_t)g * K_ + 1 + kk) * D_);
  float v = 0.f;
  #pragma unroll
  for (int it = 0; it < 4; ++it) {
    const float4 t = xp[threadIdx.x + it * 256];
    v += (t.x + t.y) + (t.z + t.w);
  }
  __shared__ float red[4];
  const float s = block_reduce_sum256(v, red);
  if (threadIdx.x == 0) mask[r] = s;
}

// fp32[r][c] (row stride ld) -> hi/lo bf16 split, same layout [r][c]
__global__ __launch_bounds__(256) void conv_kernel(
    const float* __restrict__ src, const int ld, const int cols,
    u16* __restrict__ oh, u16* __restrict__ ol)
{
  const int id = blockIdx.x * 256 + threadIdx.x;
  const int r = id / (cols >> 2), q = id - r * (cols >> 2);
  const float4 v = *(const float4*)(src + (size_t)r * ld + q * 4);
  const float vv[4] = {v.x, v.y, v.z, v.w};
  u16 h[4], lo[4];
  #pragma unroll
  for (int j = 0; j < 4; ++j) {
    h[j] = bf16rne(vv[j]);
    lo[j] = bf16rne(vv[j] - __uint_as_float((u32)h[j] << 16));
  }
  const size_t o = (size_t)r * cols + q * 4;
  *(ushort4*)(oh + o) = make_ushort4(h[0], h[1], h[2], h[3]);
  *(ushort4*)(ol + o) = make_ushort4(lo[0], lo[1], lo[2], lo[3]);
}

// fp32 [R][C] -> transposed hi/lo bf16 [C][R]
__global__ __launch_bounds__(256) void tconv_kernel(
    const float* __restrict__ src, const int R, const int C,
    u16* __restrict__ oh, u16* __restrict__ ol)
{
  __shared__ float st[64][68];
  const int t = threadIdx.x;
  const int r0 = blockIdx.y * 64, c0 = blockIdx.x * 64;
  const int lr = t >> 4, lc4 = (t & 15) * 4;
  #pragma unroll
  for (int i = 0; i < 4; ++i) {
    const float4 v = *(const float4*)(src + (size_t)(r0 + lr + 16 * i) * C + c0 + lc4);
    st[lr + 16 * i][lc4 + 0] = v.x; st[lr + 16 * i][lc4 + 1] = v.y;
    st[lr + 16 * i][lc4 + 2] = v.z; st[lr + 16 * i][lc4 + 3] = v.w;
  }
  __syncthreads();
  #pragma unroll
  for (int i = 0; i < 4; ++i) {
    const int s = t + 256 * i;
    const int c = s & 63, rq = s >> 6;   // 64 cols x 16 row-quads
    u16 h[4], lo[4];
    #pragma unroll
    for (int j = 0; j < 4; ++j) {
      const float f = st[rq * 4 + j][c];
      h[j] = bf16rne(f);
      lo[j] = bf16rne(f - __uint_as_float((u32)h[j] << 16));
    }
    const size_t o = (size_t)(c0 + c) * R + r0 + rq * 4;
    *(ushort4*)(oh + o) = make_ushort4(h[0], h[1], h[2], h[3]);
    *(ushort4*)(ol + o) = make_ushort4(lo[0], lo[1], lo[2], lo[3]);
  }
}

// bf[n] = sum_j b_obj[j] * W2[j][n]
__global__ __launch_bounds__(256) void bf_kernel(
    const float* __restrict__ b1, const float* __restrict__ W2, float* __restrict__ bf)
{
  const int n = blockIdx.x * 256 + threadIdx.x;
  float acc = 0.f;
  for (int j = 0; j < 1024; ++j) acc = fmaf(b1[j], W2[(size_t)j * 1024 + n], acc);
  bf[n] = acc;
}

// ---------------------------------------------------------------------------
// bf16x3 MFMA GEMM: C[M,N] = A @ B via Ah*Bh + Ah*Bl + Al*Bh   (fp32 acc)
// Tile 128x128, BK=32, 256 threads (4 waves, 2x2 of 64x64), mfma_f32_16x16x32_bf16.
// B is pre-split bf16 hi/lo, stored TRANSPOSED [n][k], staged via global_load_lds
// with pre-swizzled source (LDS linear, byte ^= (row&7)<<4 over 128B hi|lo row ->
// frag ds_read_b128 is <=2-way bank aliased = free).
// AMODE 0: A pre-split hi/lo [m][k] (gll).  AMODE 1: A = x rows g*20+1+kk (fp32,
// reg-staged + truncation split on the fly).  AMODE 2: A = x rows r*20.
// EPI 0: Cf = acc + bias.  EPI 1: split (acc+bias) -> Coh/Col.
// EPI 2: Cf = scale[row]*(acc + bias) + bias2  (fused obj_feat@W2 epilogue).
// ---------------------------------------------------------------------------
template<int AMODE, int EPI>
__global__ __launch_bounds__(256, 2) void mfma_gemm(
    const float* __restrict__ Af,
    const u16* __restrict__ Ah, const u16* __restrict__ Al,
    const u16* __restrict__ Bh, const u16* __restrict__ Bl,
    const float* __restrict__ bias, const float* __restrict__ bias2,
    const float* __restrict__ scale,
    float* __restrict__ Cf, u16* __restrict__ Coh, u16* __restrict__ Col,
    const int Kk, const int Nn)
{
  __shared__ alignas(16) char sm[32768];   // A: [0,16K), B: [16K,32K)
  const int t = threadIdx.x;
  const int m0 = blockIdx.x * 128, n0 = blockIdx.y * 128;
  const int w = t >> 6, l = t & 63;
  const int wm = w >> 1, wn = w & 1;

  const int srow = t >> 3;          // staging row (+32*i)
  const int sc16 = (t & 7) * 16;    // 16B chunk within 128B row

  // ---- B staging setup (gll, pre-swizzled per-lane source) ----
  const u16* bsrc[4]; int bdst[4];
  #pragma unroll
  for (int i = 0; i < 4; ++i) {
    const int row = srow + 32 * i;
    const int clog = sc16 ^ ((row & 7) << 4);     // logical byte for this phys chunk
    const u16* base = (clog & 64) ? Bl : Bh;
    bsrc[i] = base + (size_t)(n0 + row) * Kk + ((clog & 63) >> 1);
    bdst[i] = 16384 + row * 128 + sc16;
  }

  // ---- A staging setup ----
  const float* aptr[4]; int awhi[4], awlo[4];
  const u16* asrc[4]; int adst[4];
  if (AMODE == 0) {
    #pragma unroll
    for (int i = 0; i < 4; ++i) {
      const int row = srow + 32 * i;
      const int clog = sc16 ^ ((row & 7) << 4);
      const u16* base = (clog & 64) ? Al : Ah;
      asrc[i] = base + (size_t)(m0 + row) * Kk + ((clog & 63) >> 1);
      adst[i] = row * 128 + sc16;
    }
  } else {
    #pragma unroll
    for (int i = 0; i < 4; ++i) {
      const int row = srow + 32 * i;
      const int gr = m0 + row;
      size_t roff;
      if (AMODE == 1) { const int g = gr / 19, kk = gr - g * 19;
                        roff = (size_t)(g * 20 + 1 + kk) * 4096; }
      else            { roff = (size_t)gr * (20 * 4096); }
      aptr[i] = Af + roff + (t & 7) * 4;
      const int swz = (row & 7) << 4;
      awhi[i] = row * 128 + (((t & 7) * 8) ^ swz);
      awlo[i] = row * 128 + ((((t & 7) * 8) + 64) ^ swz);
    }
  }

  // ---- fragment read offsets (same swizzle) ----
  const int lk16 = (l >> 4) * 16;   // lane k-group: k = (l>>4)*8 + j
  int aoh[4], aol[4], boh[4], bol[4];
  #pragma unroll
  for (int f = 0; f < 4; ++f) {
    const int ar = wm * 64 + f * 16 + (l & 15);
    const int sa = (ar & 7) << 4;
    aoh[f] = ar * 128 + (lk16 ^ sa);
    aol[f] = ar * 128 + ((lk16 + 64) ^ sa);
    const int br = wn * 64 + f * 16 + (l & 15);
    const int sb = (br & 7) << 4;
    boh[f] = 16384 + br * 128 + (lk16 ^ sb);
    bol[f] = 16384 + br * 128 + ((lk16 + 64) ^ sb);
  }

  f32x4 acc[4][4] = {};
  const int nk = Kk >> 5;
  for (int kt = 0; kt < nk; ++kt) {
    // stage B (+A if pre-split) via global_load_lds
    #pragma unroll
    for (int i = 0; i < 4; ++i) gll16(bsrc[i] + kt * 32, sm + bdst[i]);
    if (AMODE == 0) {
      #pragma unroll
      for (int i = 0; i < 4; ++i) gll16(asrc[i] + kt * 32, sm + adst[i]);
    } else {
      // fp32 A tile: load float4, truncation-split hi/lo (exact: lo = x - trunc16(x)),
      // residual ~2^-16 rel; write packed b64 to swizzled LDS.
      #pragma unroll
      for (int i = 0; i < 4; ++i) {
        const float4 v = *(const float4*)(aptr[i] + kt * 32);
        const u32 u0 = __float_as_uint(v.x), u1 = __float_as_uint(v.y);
        const u32 u2 = __float_as_uint(v.z), u3 = __float_as_uint(v.w);
        const u32 h01 = (u0 >> 16) | (u1 & 0xffff0000u);
        const u32 h23 = (u2 >> 16) | (u3 & 0xffff0000u);
        const float l0 = v.x - __uint_as_float(u0 & 0xffff0000u);
        const float l1 = v.y - __uint_as_float(u1 & 0xffff0000u);
        const float l2 = v.z - __uint_as_float(u2 & 0xffff0000u);
        const float l3 = v.w - __uint_as_float(u3 & 0xffff0000u);
        const u32 lo01 = (__float_as_uint(l0) >> 16) | (__float_as_uint(l1) & 0xffff0000u);
        const u32 lo23 = (__float_as_uint(l2) >> 16) | (__float_as_uint(l3) & 0xffff0000u);
        *(uint2*)(sm + awhi[i]) = make_uint2(h01, h23);
        *(uint2*)(sm + awlo[i]) = make_uint2(lo01, lo23);
      }
    }
    __syncthreads();   // drains vmcnt (gll) + lgkm (ds_write)

    bf16x8 ah[4], alo[4], bh[4], blo[4];
    #pragma unroll
    for (int f = 0; f < 4; ++f) {
      ah[f]  = *(const bf16x8*)(sm + aoh[f]);
      alo[f] = *(const bf16x8*)(sm + aol[f]);
      bh[f]  = *(const bf16x8*)(sm + boh[f]);
      blo[f] = *(const bf16x8*)(sm + bol[f]);
    }
    #pragma unroll
    for (int mi = 0; mi < 4; ++mi)
      #pragma unroll
      for (int ni = 0; ni < 4; ++ni) {
        acc[mi][ni] = __builtin_amdgcn_mfma_f32_16x16x32_bf16(ah[mi],  bh[ni],  acc[mi][ni], 0, 0, 0);
        acc[mi][ni] = __builtin_amdgcn_mfma_f32_16x16x32_bf16(ah[mi],  blo[ni], acc[mi][ni], 0, 0, 0);
        acc[mi][ni] = __builtin_amdgcn_mfma_f32_16x16x32_bf16(alo[mi], bh[ni],  acc[mi][ni], 0, 0, 0);
      }
    __syncthreads();   // protect LDS before next stage
  }

  // ---- epilogue (C/D: row = (l>>4)*4 + r, col = l&15) ----
  #pragma unroll
  for (int mi = 0; mi < 4; ++mi) {
    const int gr0 = m0 + wm * 64 + mi * 16 + ((l >> 4) << 2);
    #pragma unroll
    for (int ni = 0; ni < 4; ++ni) {
      const int gc = n0 + wn * 64 + ni * 16 + (l & 15);
      const float bb = bias ? bias[gc] : 0.0f;
      const float b2v = (EPI == 2) ? bias2[gc] : 0.0f;
      const f32x4 v = acc[mi][ni];
      #pragma unroll
      for (int r = 0; r < 4; ++r) {
        const int gr = gr0 + r;
        const size_t o = (size_t)gr * Nn + gc;
        if (EPI == 0) {
          Cf[o] = v[r] + bb;
        } else if (EPI == 1) {
          const float fv = v[r] + bb;
          const u16 h = bf16rne(fv);
          Coh[o] = h;
          Col[o] = bf16rne(fv - __uint_as_float((u32)h << 16));
        } else {
          Cf[o] = scale[gr] * (v[r] + bb) + b2v;
        }
      }
    }
  }
}

// ---------------------------------------------------------------------------
// Scan kernels (unchanged)
// ---------------------------------------------------------------------------

// attn hidden partials: ahp[isl][b][j] = sum_{i in slice} hB[b][i] * Wah[i][j]
__global__ __launch_bounds__(256) void attn_h_kernel(
    const float* __restrict__ hB, const float* __restrict__ Wah, float* __restrict__ ahp)
{
  const int j = blockIdx.x * 256 + threadIdx.x;
  const int isl = blockIdx.y;
  float acc[B_] = {};
  for (int i0 = 0; i0 < 128; i0 += 4) {
    const int i = isl * 128 + i0;
    const float w0 = Wah[(size_t)(i + 0) * DO_ + j];
    const float w1 = Wah[(size_t)(i + 1) * DO_ + j];
    const float w2 = Wah[(size_t)(i + 2) * DO_ + j];
    const float w3 = Wah[(size_t)(i + 3) * DO_ + j];
    #pragma unroll
    for (int b = 0; b < B_; ++b) {
      const float4 hv = *(const float4*)(hB + b * H_ + i);  // wave-uniform scalar load
      acc[b] = fmaf(hv.x, w0, fmaf(hv.y, w1, fmaf(hv.z, w2, fmaf(hv.w, w3, acc[b]))));
    }
  }
  #pragma unroll
  for (int b = 0; b < B_; ++b) ahp[((size_t)isl * B_ + b) * DO_ + j] = acc[b];
}

// scores + softmax + w_obj, one block per batch element b.
__global__ __launch_bounds__(256) void attn_rest_kernel(
    const float* __restrict__ ahp, const float* __restrict__ a,
    const float* __restrict__ wj, const float* __restrict__ mask,
    const int n, float* __restrict__ alphas_out, float* __restrict__ wobj)
{
  const int b = blockIdx.x, tid = threadIdx.x;
  __shared__ float ahs[DO_];       // 4 KB
  __shared__ float wjs[DO_];       // 4 KB
  __shared__ float as_[KM1][DO_];  // 76 KB
  __shared__ float sc[KM1 + 1];
  const size_t rowbase = (size_t)(b * N_ + n) * KM1;
  #pragma unroll
  for (int it = 0; it < 4; ++it) {
    const int j = tid + it * 256;
    float s = 0.f;
    #pragma unroll
    for (int sl = 0; sl < 8; ++sl) s += ahp[((size_t)sl * B_ + b) * DO_ + j];
    ahs[j] = s;
    wjs[j] = wj[j];
  }
  #pragma unroll
  for (int it = 0; it < 19; ++it) {
    const int i = tid + it * 256;
    const int k = i >> 8, jj = (i & 255) * 4;
    *(float4*)&as_[k][jj] = *(const float4*)(a + (rowbase + k) * DO_ + jj);
  }
  __syncthreads();
  const int w = tid >> 6, lane = tid & 63;
  for (int k = w; k < KM1; k += 4) {
    float v = 0.f;
    #pragma unroll
    for (int it = 0; it < 16; ++it) {
      const int j = lane + it * 64;
      v = fmaf(tanhf(ahs[j] + as_[k][j]), wjs[j], v);
    }
    #pragma unroll
    for (int off = 32; off > 0; off >>= 1) v += __shfl_down(v, off);
    if (lane == 0) sc[k] = v * mask[rowbase + k];
  }
  __syncthreads();
  float mx = -1e30f;
  #pragma unroll
  for (int k = 0; k < KM1; ++k) mx = fmaxf(mx, sc[k]);
  float al[KM1];
  float ssum = 0.f;
  #pragma unroll
  for (int k = 0; k < KM1; ++k) { al[k] = expf(sc[k] - mx); ssum += al[k]; }
  const float inv = 1.0f / ssum;
  if (tid < KM1) alphas_out[b * KM1 + tid] = al[tid] * inv;
  #pragma unroll
  for (int it = 0; it < 4; ++it) {
    const int j = tid + it * 256;
    float acc = 0.f;
    #pragma unroll
    for (int k = 0; k < KM1; ++k) acc = fmaf(al[k], as_[k][j], acc);
    wobj[b * DO_ + j] = acc * inv;
  }
}

// LSTM gate partials
__global__ __launch_bounds__(256) void gates_kernel(
    const float* __restrict__ x0, const float* __restrict__ x1,
    const float* __restrict__ W0, const int ld0, const int co0,
    const float* __restrict__ W1, const int ld1, const int co1,
    float* __restrict__ gp)
{
  constexpr int GT = 256, BK = 32, KSL = 128;
  __shared__ float Ws[BK][GT + 4];
  __shared__ float Xs[BK][20];
  const int tid = threadIdx.x;
  const int g0 = blockIdx.x * GT;
  const int ks = blockIdx.y;
  const int half = ks >> 3;
  const int koff = (ks & 7) * KSL;
  const float* X = half ? x1 : x0;
  const float* W = half ? W1 : W0;
  const int ld = half ? ld1 : ld0;
  const int co = half ? co1 : co0;
  const int tb = (tid & 7) * 2;
  const int tg = (tid >> 3) * 8;
  const float* wbase = W + (size_t)(g0 + (tid >> 3)) * ld + co + koff + (tid & 7) * 4;
  const int xb = tid & 15, xkq = (tid >> 4) * 4;

  float acc[2][8] = {};
  for (int k0 = 0; k0 < KSL; k0 += BK) {
    #pragma unroll
    for (int it = 0; it < 8; ++it) {
      const int gr = (tid >> 3) + it * 32;
      const int kq = (tid & 7) * 4;
      const float4 v = *(const float4*)(wbase + (size_t)it * 32 * ld + k0);
      Ws[kq + 0][gr] = v.x; Ws[kq + 1][gr] = v.y;
      Ws[kq + 2][gr] = v.z; Ws[kq + 3][gr] = v.w;
    }
    if (tid < 128) {
      const float4 v = *(const float4*)(X + (size_t)xb * H_ + koff + k0 + xkq);
      Xs[xkq + 0][xb] = v.x; Xs[xkq + 1][xb] = v.y;
      Xs[xkq + 2][xb] = v.z; Xs[xkq + 3][xb] = v.w;
    }
    __syncthreads();
    #pragma unroll
    for (int k = 0; k < BK; ++k) {
      float wv[8], xv[2];
      *(float4*)&wv[0] = *(const float4*)&Ws[k][tg];
      *(float4*)&wv[4] = *(const float4*)&Ws[k][tg + 4];
      *(float2*)&xv[0] = *(const float2*)&Xs[k][tb];
      #pragma unroll
      for (int bi = 0; bi < 2; ++bi)
        #pragma unroll
        for (int gi = 0; gi < 8; ++gi)
          acc[bi][gi] = fmaf(wv[gi], xv[bi], acc[bi][gi]);
    }
    __syncthreads();
  }
  float* outp = gp + (size_t)ks * B_ * G4_;
  #pragma unroll
  for (int bi = 0; bi < 2; ++bi) {
    float* op = outp + (size_t)(tb + bi) * G4_ + g0 + tg;
    *(float4*)(op)     = *(const float4*)&acc[bi][0];
    *(float4*)(op + 4) = *(const float4*)&acc[bi][4];
  }
}

__global__ __launch_bounds__(256) void cell0_kernel(
    const float* __restrict__ gp, const float* __restrict__ img_gates, const int n,
    float* __restrict__ hA, float* __restrict__ cA)
{
  const int idx = blockIdx.x * 256 + threadIdx.x;
  const int b = idx >> 10, j = idx & 1023;
  const float* ig = img_gates + ((size_t)(b * N_ + n)) * G4_;
  float gi = ig[j], gf = ig[1024 + j], gg = ig[2048 + j], go = ig[3072 + j];
  #pragma unroll
  for (int s = 0; s < 16; ++s) {
    const float* p = gp + ((size_t)s * B_ + b) * G4_;
    gi += p[j]; gf += p[1024 + j]; gg += p[2048 + j]; go += p[3072 + j];
  }
  const float c = cA[idx];
  const float cn = sigmoidf_(gf) * c + sigmoidf_(gi) * tanhf(gg);
  const float hn = sigmoidf_(go) * tanhf(cn);
  cA[idx] = cn; hA[idx] = hn;
}

__global__ __launch_bounds__(256) void cell1_kernel(
    const float* __restrict__ gp, const float* __restrict__ b1,
    const float* __restrict__ Wout,
    float* __restrict__ hB, float* __restrict__ cB, float* __restrict__ pred_acc)
{
  const int b = blockIdx.x >> 2, jq = blockIdx.x & 3, tid = threadIdx.x;
  const int j = jq * 256 + tid;
  float gi = b1[j], gf = b1[1024 + j], gg = b1[2048 + j], go = b1[3072 + j];
  #pragma unroll
  for (int s = 0; s < 16; ++s) {
    const float* p = gp + ((size_t)s * B_ + b) * G4_;
    gi += p[j]; gf += p[1024 + j]; gg += p[2048 + j]; go += p[3072 + j];
  }
  const int idx = b * H_ + j;
  const float c = cB[idx];
  const float cn = sigmoidf_(gf) * c + sigmoidf_(gi) * tanhf(gg);
  const float hn = sigmoidf_(go) * tanhf(cn);
  cB[idx] = cn; hB[idx] = hn;
  float part = hn * Wout[j];
  __shared__ float red[4];
  const float s = block_reduce_sum256(part, red);
  if (tid == 0) atomicAdd(&pred_acc[b], s);
}

__global__ __launch_bounds__(256) void pred_kernel(
    const float* __restrict__ pred_acc, const float* __restrict__ bout,
    float* __restrict__ out_pred)
{
  const float bo = bout[0];
  #pragma unroll
  for (int it = 0; it < 4; ++it) {
    const int i = threadIdx.x + it * 256;
    out_pred[i] = 1.0f / (1.0f + expf(-(pred_acc[i] + bo)));
  }
}

extern "C" void kernel_launch(void* const* d_in, const int* in_sizes, int n_in,
                              void* d_out, int out_size, void* d_ws, size_t ws_size,
                              hipStream_t stream) {
  const float* x       = (const float*)d_in[0];
  const float* W_img   = (const float*)d_in[1];
  const float* b_img   = (const float*)d_in[2];
  const float* W_obj   = (const float*)d_in[3];
  const float* b_obj   = (const float*)d_in[4];
  const float* W_obj2  = (const float*)d_in[5];
  const float* b_obj2  = (const float*)d_in[6];
  const float* W_attn_h= (const float*)d_in[7];
  const float* W_attn_j= (const float*)d_in[8];
  const float* W_ih0   = (const float*)d_in[9];    // (4096, 2048)
  const float* W_hh0   = (const float*)d_in[10];   // (4096, 1024)
  const float* b0      = (const float*)d_in[11];
  const float* W_ih1   = (const float*)d_in[12];
  const float* W_hh1   = (const float*)d_in[13];
  const float* b1      = (const float*)d_in[14];
  const float* W_out   = (const float*)d_in[15];
  const float* b_out   = (const float*)d_in[16];
  float* out = (float*)d_out;

  // workspace layout: same footprint as before; regionA = old obj_feat slot (76.2MB)
  float* ws = (float*)d_ws;
  float* mask     = ws;                                   // 19456
  char*  rA       = (char*)(mask + 19456);                // 19456*1024 floats
  float* a_buf    = (float*)(rA + (size_t)19456 * 4096);  // 19456*1024 floats
  float* ahp      = a_buf + (size_t)19456 * 1024;         // 8*16*1024
  float* wobj     = ahp + 8 * B_ * DO_;                   // 16*1024
  float* hA       = wobj + B_ * DO_;
  float* cA       = hA + B_ * H_;
  float* hB       = cA + B_ * H_;
  float* cB       = hB + B_ * H_;
  float* pred_acc = cB + B_ * H_;                         // 1024 (N*B)
  float* gp       = pred_acc + N_ * B_;                   // 16*16*4096

  // conversion buffers inside regionA (lifetimes checked, 68MB < 76.2MB):
  const size_t MB = 1u << 20;
  u16* W1c_h   = (u16*)(rA);              // [0,8)   dead after GEMM5
  u16* W1c_l   = (u16*)(rA +  8 * MB);    // [8,16)  dead after GEMM5
  u16* W2t_h   = (u16*)(rA + 16 * MB);    // [16,18) dead after GEMM5
  u16* W2t_l   = (u16*)(rA + 18 * MB);    // [18,20) dead after GEMM5
  u16* Wft_h   = (u16*)(rA + 20 * MB);    // [20,28) dead after GEMM1
  u16* Wft_l   = (u16*)(rA + 28 * MB);    // [28,36) dead after GEMM1
  u16* Wimgt_h = (u16*)(rA + 36 * MB);    // [36,44) dead after GEMM3
  u16* Wimgt_l = (u16*)(rA + 44 * MB);    // [44,52) dead after GEMM3
  u16* Wih0c_h = (u16*)(rA + 52 * MB);    // [52,60) dead after GEMM4
  u16* Wih0c_l = (u16*)(rA + 60 * MB);    // [60,68) dead after GEMM4
  u16* img_h   = (u16*)(rA);              // [0,2)  written by GEMM3 (W1c dead)
  u16* img_l   = (u16*)(rA +  2 * MB);    // [2,4)
  float* img_gates = (float*)(rA + 4 * MB); // [4,20) written by GEMM4, live in scan
  float* bfv   = (float*)(rA + 68 * MB);  // 1024 floats

  hipMemsetAsync(hA, 0, ((size_t)4 * B_ * H_ + N_ * B_) * sizeof(float), stream);

  // ---- feedforward ----
  mask_kernel<<<19456, 256, 0, stream>>>(x, mask);
  conv_kernel<<<4096, 256, 0, stream>>>(W_obj, 1024, 1024, W1c_h, W1c_l);
  tconv_kernel<<<dim3(16, 16), 256, 0, stream>>>(W_obj2, 1024, 1024, W2t_h, W2t_l);
  conv_kernel<<<4096, 256, 0, stream>>>(W_ih0, 2048, 1024, Wih0c_h, Wih0c_l);
  tconv_kernel<<<dim3(16, 64), 256, 0, stream>>>(W_img, 4096, 1024, Wimgt_h, Wimgt_l);
  bf_kernel<<<4, 256, 0, stream>>>(b_obj, W_obj2, bfv);

  // GEMM5: Wft[n][d] = sum_j W2t[n][j] * W1[d][j]  (= (W_obj@W_obj2)^T), split output
  mfma_gemm<0, 1><<<dim3(8, 32), 256, 0, stream>>>(
      nullptr, W2t_h, W2t_l, W1c_h, W1c_l,
      nullptr, nullptr, nullptr, nullptr, Wft_h, Wft_l, 1024, 4096);
  // GEMM1 (fused): a[r][n] = mask[r]*((x_r @ Wf)[n] + bf[n]) + b_obj2[n]
  mfma_gemm<1, 2><<<dim3(152, 8), 256, 0, stream>>>(
      x, nullptr, nullptr, Wft_h, Wft_l,
      bfv, b_obj2, mask, a_buf, nullptr, nullptr, 4096, 1024);
  // GEMM3: img_feat = x_img @ W_img + b_img, split output
  mfma_gemm<2, 1><<<dim3(8, 8), 256, 0, stream>>>(
      x, nullptr, nullptr, Wimgt_h, Wimgt_l,
      b_img, nullptr, nullptr, nullptr, img_h, img_l, 4096, 1024);
  // GEMM4: img_gates = img_feat @ W_ih0[:, :1024]^T + b0
  mfma_gemm<0, 0><<<dim3(8, 32), 256, 0, stream>>>(
      nullptr, img_h, img_l, Wih0c_h, Wih0c_l,
      b0, nullptr, nullptr, img_gates, nullptr, nullptr, 1024, 4096);

  // ---- sequential scan (unchanged) ----
  for (int n = 0; n < N_; ++n) {
    attn_h_kernel<<<dim3(4, 8), 256, 0, stream>>>(hB, W_attn_h, ahp);
    attn_rest_kernel<<<B_, 256, 0, stream>>>(ahp, a_buf, W_attn_j, mask, n,
                                             out + (size_t)n * (B_ * KM1), wobj);
    gates_kernel<<<dim3(16, 16), 256, 0, stream>>>(wobj, hA, W_ih0, 2048, 1024,
                                                   W_hh0, 1024, 0, gp);
    cell0_kernel<<<64, 256, 0, stream>>>(gp, img_gates, n, hA, cA);
    gates_kernel<<<dim3(16, 16), 256, 0, stream>>>(hA, hB, W_ih1, 1024, 0,
                                                   W_hh1, 1024, 0, gp);
    cell1_kernel<<<64, 256, 0, stream>>>(gp, b1, W_out, hB, cB, pred_acc + n * B_);
  }
  pred_kernel<<<1, 256, 0, stream>>>(pred_acc, b_out, out + (size_t)N_ * B_ * KM1);
}